// Round 3
// baseline (84.214 us; speedup 1.0000x reference)
//
#include <hip/hip_runtime.h>
#include <math.h>

#define B_ROWS 8192
#define D_DIM 512
#define N_LABELS 256
#define TCAP 48            // partner rows staged per LDS tile (P[cnt>48] ~ 0.3%)
#define TSTRIDE 520        // bf16 elems per staged row (512+8 pad)
#define POS_PER_BLOCK 16   // bucket positions per block (flat decomposition)

static __device__ __forceinline__ unsigned int f2bf(float f) {
    // round-to-nearest-even fp32 -> bf16 bits
    unsigned int u = __float_as_uint(f);
    return (u + 0x7FFFu + ((u >> 16) & 1u)) >> 16;
}
static __device__ __forceinline__ float bf_lo(unsigned int u) {
    return __uint_as_float(u << 16);
}
static __device__ __forceinline__ float bf_hi(unsigned int u) {
    return __uint_as_float(u & 0xFFFF0000u);
}

// ---------------- fused: per-row |z|^2 + bucketing (one block per label) ----------------
__global__ __launch_bounds__(256) void bucket_kernel(const float* __restrict__ z,
                                                     const int* __restrict__ Mx,
                                                     int* __restrict__ counts,
                                                     int* __restrict__ offsets,
                                                     int* __restrict__ bucket,
                                                     float* __restrict__ sqf) {
    __shared__ int hist[N_LABELS];
    __shared__ int wsum[4];
    __shared__ int off_sh;
    const int tid  = threadIdx.x;
    const int lbl  = blockIdx.x;
    const int wv   = tid >> 6;
    const int lane = tid & 63;

    // ---- part 1: |z|^2 for 32 rows (wave per row, 8 rows per wave) ----
    for (int rr = 0; rr < 8; ++rr) {
        const int row = blockIdx.x * 32 + wv * 8 + rr;
        const float* zp = z + (size_t)row * D_DIM + lane * 8;
        const float4 v0 = *(const float4*)(zp);
        const float4 v1 = *(const float4*)(zp + 4);
        float s = v0.x*v0.x + v0.y*v0.y + v0.z*v0.z + v0.w*v0.w
                + v1.x*v1.x + v1.y*v1.y + v1.z*v1.z + v1.w*v1.w;
        s += __shfl_xor(s, 1, 64);
        s += __shfl_xor(s, 2, 64);
        s += __shfl_xor(s, 4, 64);
        s += __shfl_xor(s, 8, 64);
        s += __shfl_xor(s, 16, 64);
        s += __shfl_xor(s, 32, 64);
        if (lane == 0) sqf[row] = s;
    }

    // ---- part 2: histogram + exclusive offset + deterministic scatter ----
    hist[tid] = 0;
    __syncthreads();
    for (int i = tid; i < B_ROWS; i += 256) atomicAdd(&hist[Mx[i]], 1);
    __syncthreads();

    int partial = (tid < lbl) ? hist[tid] : 0;
    partial += __shfl_xor(partial, 1, 64);
    partial += __shfl_xor(partial, 2, 64);
    partial += __shfl_xor(partial, 4, 64);
    partial += __shfl_xor(partial, 8, 64);
    partial += __shfl_xor(partial, 16, 64);
    partial += __shfl_xor(partial, 32, 64);
    if ((tid & 63) == 0) wsum[tid >> 6] = partial;
    __syncthreads();
    if (tid == 0) {
        const int off = wsum[0] + wsum[1] + wsum[2] + wsum[3];
        off_sh = off;
        offsets[lbl] = off;
        counts[lbl]  = hist[lbl];
    }
    __syncthreads();

    if (tid < 64) {
        int pos = off_sh;
        const unsigned long long lower = (tid == 0) ? 0ull : ((1ull << tid) - 1ull);
        for (int base = 0; base < B_ROWS; base += 64) {
            const bool match = (Mx[base + tid] == lbl);
            const unsigned long long bal = __ballot(match);
            if (match) bucket[pos + __popcll(bal & lower)] = base + tid;
            pos += __popcll(bal);
        }
    }
}

// ---------------- main loss kernel ----------------
// Flat decomposition: block b owns bucket positions [16b, 16b+16).
// 512 threads = 8 waves; half-wave per position. For each label present in the
// range, stage its group rows (bf16) + |z|^2 in LDS, then matching halves
// compute. Inner loop: dot-product trick, 4 independent fma chains.
__global__ __launch_bounds__(512) void loss_kernel(const float* __restrict__ z,
                                                   const int* __restrict__ Mx,
                                                   const int* __restrict__ counts,
                                                   const int* __restrict__ offsets,
                                                   const int* __restrict__ bucket,
                                                   const float* __restrict__ sqf,
                                                   float* __restrict__ out) {
    __shared__ __align__(16) unsigned short tile[TCAP * TSTRIDE]; // 49,920 B
    __shared__ int   ids[TCAP];
    __shared__ float sqt[TCAP];

    const int tid  = threadIdx.x;
    const int wv   = tid >> 6;
    const int lane = tid & 63;
    const int h    = lane >> 5;
    const int jl   = lane & 31;

    const int p0    = blockIdx.x * POS_PER_BLOCK;
    const int p     = p0 + wv * 2 + h;          // this half-wave's bucket position
    const int i_id  = bucket[p];
    const int gmine = Mx[i_id];
    const int glo   = Mx[bucket[p0]];
    const int ghi   = Mx[bucket[p0 + POS_PER_BLOCK - 1]];

    const float sq_i = sqf[i_id];
    const float* __restrict__ abase = z + (size_t)i_id * D_DIM;
    float acc = 0.f;

    for (int g = glo; g <= ghi; ++g) {
        const int off = offsets[g];
        const int cnt = counts[g];
        for (int tb = 0; tb < cnt; tb += TCAP) {
            const int cnt_t = min(TCAP, cnt - tb);

            // ---- stage group rows fp32 -> bf16, plus ids and |z|^2 ----
            for (int c = tid; c < cnt_t; c += 512) {
                const int jid = bucket[off + tb + c];
                ids[c] = jid;
                sqt[c] = sqf[jid];
            }
            for (int c = tid; c < cnt_t * (D_DIM / 4); c += 512) {
                const int row = c >> 7;              // D_DIM/4 == 128
                const int col = c & 127;
                const int jid = bucket[off + tb + row];
                const float4 v = *(const float4*)(z + (size_t)jid * D_DIM + col * 4);
                uint2 pk;
                pk.x = f2bf(v.x) | (f2bf(v.y) << 16);
                pk.y = f2bf(v.z) | (f2bf(v.w) << 16);
                *(uint2*)(&tile[row * TSTRIDE + col * 4]) = pk;
            }
            __syncthreads();

            if (gmine == g) {
                const int njt = (cnt_t + 31) >> 5;
                for (int jt = 0; jt < njt; ++jt) {
                    const int j_sub = jt * 32 + jl;
                    const bool jval = (j_sub < cnt_t);
                    const int j_eff = jval ? j_sub : 0;
                    const unsigned short* __restrict__ bp = &tile[j_eff * TSTRIDE];

                    float s0 = 0.f, s1 = 0.f, s2 = 0.f, s3 = 0.f;
                    #pragma unroll
                    for (int d = 0; d < D_DIM; d += 32) {
                        const uint4 b0 = *(const uint4*)(bp + d);
                        const uint4 b1 = *(const uint4*)(bp + d + 8);
                        const uint4 b2 = *(const uint4*)(bp + d + 16);
                        const uint4 b3 = *(const uint4*)(bp + d + 24);
                        const float4 a0 = *(const float4*)(abase + d);
                        const float4 a1 = *(const float4*)(abase + d + 4);
                        const float4 a2 = *(const float4*)(abase + d + 8);
                        const float4 a3 = *(const float4*)(abase + d + 12);
                        const float4 a4 = *(const float4*)(abase + d + 16);
                        const float4 a5 = *(const float4*)(abase + d + 20);
                        const float4 a6 = *(const float4*)(abase + d + 24);
                        const float4 a7 = *(const float4*)(abase + d + 28);

                        s0 = fmaf(a0.x, bf_lo(b0.x), s0);
                        s0 = fmaf(a0.y, bf_hi(b0.x), s0);
                        s0 = fmaf(a0.z, bf_lo(b0.y), s0);
                        s0 = fmaf(a0.w, bf_hi(b0.y), s0);
                        s0 = fmaf(a1.x, bf_lo(b0.z), s0);
                        s0 = fmaf(a1.y, bf_hi(b0.z), s0);
                        s0 = fmaf(a1.z, bf_lo(b0.w), s0);
                        s0 = fmaf(a1.w, bf_hi(b0.w), s0);

                        s1 = fmaf(a2.x, bf_lo(b1.x), s1);
                        s1 = fmaf(a2.y, bf_hi(b1.x), s1);
                        s1 = fmaf(a2.z, bf_lo(b1.y), s1);
                        s1 = fmaf(a2.w, bf_hi(b1.y), s1);
                        s1 = fmaf(a3.x, bf_lo(b1.z), s1);
                        s1 = fmaf(a3.y, bf_hi(b1.z), s1);
                        s1 = fmaf(a3.z, bf_lo(b1.w), s1);
                        s1 = fmaf(a3.w, bf_hi(b1.w), s1);

                        s2 = fmaf(a4.x, bf_lo(b2.x), s2);
                        s2 = fmaf(a4.y, bf_hi(b2.x), s2);
                        s2 = fmaf(a4.z, bf_lo(b2.y), s2);
                        s2 = fmaf(a4.w, bf_hi(b2.y), s2);
                        s2 = fmaf(a5.x, bf_lo(b2.z), s2);
                        s2 = fmaf(a5.y, bf_hi(b2.z), s2);
                        s2 = fmaf(a5.z, bf_lo(b2.w), s2);
                        s2 = fmaf(a5.w, bf_hi(b2.w), s2);

                        s3 = fmaf(a6.x, bf_lo(b3.x), s3);
                        s3 = fmaf(a6.y, bf_hi(b3.x), s3);
                        s3 = fmaf(a6.z, bf_lo(b3.y), s3);
                        s3 = fmaf(a6.w, bf_hi(b3.y), s3);
                        s3 = fmaf(a7.x, bf_lo(b3.z), s3);
                        s3 = fmaf(a7.y, bf_hi(b3.z), s3);
                        s3 = fmaf(a7.z, bf_lo(b3.w), s3);
                        s3 = fmaf(a7.w, bf_hi(b3.w), s3);
                    }
                    const float dot = (s0 + s1) + (s2 + s3);
                    const int   j_id = ids[j_eff];
                    const float d2   = sq_i + sqt[j_eff] - 2.f * dot;
                    if (jval && (j_id != i_id) && (d2 > 0.f)) acc += sqrtf(d2);
                }
            }
            __syncthreads();
        }
    }

    // one butterfly per position (within each 32-lane half)
    acc += __shfl_xor(acc, 1, 64);
    acc += __shfl_xor(acc, 2, 64);
    acc += __shfl_xor(acc, 4, 64);
    acc += __shfl_xor(acc, 8, 64);
    acc += __shfl_xor(acc, 16, 64);

    if (jl == 0) {
        const int cnt_m = counts[gmine];
        out[i_id] = (cnt_m > 1) ? acc / (float)(cnt_m - 1) : 0.f;
    }
}

// ---------------- launch ----------------
extern "C" void kernel_launch(void* const* d_in, const int* in_sizes, int n_in,
                              void* d_out, int out_size, void* d_ws, size_t ws_size,
                              hipStream_t stream) {
    const float* z  = (const float*)d_in[0];
    const int*   Mx = (const int*)d_in[1];
    float*       out = (float*)d_out;

    int*   counts  = (int*)d_ws;             // [256]
    int*   offsets = counts + N_LABELS;      // [256]
    int*   bucket  = offsets + N_LABELS;     // [8192]
    float* sqf     = (float*)(bucket + B_ROWS); // [8192]

    bucket_kernel<<<N_LABELS, 256, 0, stream>>>(z, Mx, counts, offsets, bucket, sqf);

    const int blocks = B_ROWS / POS_PER_BLOCK;   // 512
    loss_kernel<<<blocks, 512, 0, stream>>>(z, Mx, counts, offsets, bucket, sqf, out);
}

// Round 4
// 22.882 us; speedup vs baseline: 3.6804x; 3.6804x over previous
//
#include <hip/hip_runtime.h>
#include <math.h>

#define B_ROWS 8192
#define D_DIM 512
#define N_LABELS 256
#define GMAX 64            // max group size handled by MFMA path (P[exceed] ~ 1e-6)
#define KC 128             // K-chunk staged per LDS pass
#define NCHUNK (D_DIM / KC)
#define THREADS 512
#define WAVES 8
#define LSTRIDE (KC + 8)   // 136 bf16 -> 272B row stride (2-way bank alias only)

typedef __attribute__((ext_vector_type(8))) short bf16x8;
typedef __attribute__((ext_vector_type(4))) float f32x4;

static __device__ __forceinline__ unsigned int f2bf(float f) {
    // RNE fp32 -> bf16 bits
    unsigned int u = __float_as_uint(f);
    return (u + 0x7FFFu + ((u >> 16) & 1u)) >> 16;
}
static __device__ __forceinline__ float bfval(unsigned int b) {
    return __uint_as_float(b << 16);
}

// ---------------- K1: bucketing, no histogram ----------------
// offset[lbl] = #{Mx[i] < lbl}; count[lbl] = #{Mx[i] == lbl}.
// Stable scatter: 4 waves, each owns a quarter of the rows.
__global__ __launch_bounds__(256) void bucket_kernel(const int* __restrict__ Mx,
                                                     int* __restrict__ counts,
                                                     int* __restrict__ offsets,
                                                     int* __restrict__ bucket) {
    __shared__ int qe[4], ql[4], base[4];
    const int lbl  = blockIdx.x;
    const int tid  = threadIdx.x;
    const int wv   = tid >> 6;
    const int lane = tid & 63;
    const int Q    = B_ROWS / 4;       // 2048
    const int qb   = wv * Q;

    int ce = 0, cl = 0;
    for (int i = lane; i < Q; i += 64) {
        const int m = Mx[qb + i];
        ce += (m == lbl);
        cl += (m < lbl);
    }
    ce += __shfl_xor(ce, 1, 64);  cl += __shfl_xor(cl, 1, 64);
    ce += __shfl_xor(ce, 2, 64);  cl += __shfl_xor(cl, 2, 64);
    ce += __shfl_xor(ce, 4, 64);  cl += __shfl_xor(cl, 4, 64);
    ce += __shfl_xor(ce, 8, 64);  cl += __shfl_xor(cl, 8, 64);
    ce += __shfl_xor(ce, 16, 64); cl += __shfl_xor(cl, 16, 64);
    ce += __shfl_xor(ce, 32, 64); cl += __shfl_xor(cl, 32, 64);
    if (lane == 0) { qe[wv] = ce; ql[wv] = cl; }
    __syncthreads();
    if (tid == 0) {
        const int offv = ql[0] + ql[1] + ql[2] + ql[3];
        counts[lbl]  = qe[0] + qe[1] + qe[2] + qe[3];
        offsets[lbl] = offv;
        int b = offv;
        for (int w = 0; w < 4; ++w) { base[w] = b; b += qe[w]; }
    }
    __syncthreads();

    int pos = base[wv];
    const unsigned long long lower = (lane == 0) ? 0ull : ((1ull << lane) - 1ull);
    for (int c = 0; c < Q; c += 64) {
        const int row = qb + c + lane;
        const bool match = (Mx[row] == lbl);
        const unsigned long long bal = __ballot(match);
        if (match) bucket[pos + __popcll(bal & lower)] = row;
        pos += __popcll(bal);
    }
}

// ---------------- K2: per-label gram via MFMA + distance epilogue ----------------
__global__ __launch_bounds__(THREADS) void loss_kernel(const float* __restrict__ z,
                                                       const int* __restrict__ counts,
                                                       const int* __restrict__ offsets,
                                                       const int* __restrict__ bucket,
                                                       float* __restrict__ out) {
    __shared__ __align__(16) unsigned short hi_sh[GMAX][LSTRIDE];
    __shared__ __align__(16) unsigned short lo_sh[GMAX][LSTRIDE];
    __shared__ float sq_sh[GMAX];
    __shared__ int   ids_sh[GMAX];
    __shared__ float rowpart[WAVES][GMAX];

    const int lbl = blockIdx.x;
    const int cnt = counts[lbl];
    if (cnt <= 0) return;
    const int off  = offsets[lbl];
    const int tid  = threadIdx.x;
    const int wv   = tid >> 6;
    const int lane = tid & 63;

    if (cnt > GMAX) {
        // exact fp32 fallback (never runs for this data; correctness guard)
        for (int r = wv; r < cnt; r += WAVES) {
            const int i_id = bucket[off + r];
            float acc = 0.f;
            for (int jj = 0; jj < cnt; ++jj) {
                const int j_id = bucket[off + jj];
                if (j_id == i_id) continue;
                float s = 0.f;
                for (int d = lane; d < D_DIM; d += 64) {
                    const float t = z[(size_t)i_id * D_DIM + d] - z[(size_t)j_id * D_DIM + d];
                    s = fmaf(t, t, s);
                }
                s += __shfl_xor(s, 1, 64);
                s += __shfl_xor(s, 2, 64);
                s += __shfl_xor(s, 4, 64);
                s += __shfl_xor(s, 8, 64);
                s += __shfl_xor(s, 16, 64);
                s += __shfl_xor(s, 32, 64);
                acc += (s > 0.f) ? sqrtf(s) : 0.f;
            }
            if (lane == 0) out[i_id] = acc / (float)(cnt - 1);
        }
        return;
    }

    if (tid < cnt) ids_sh[tid] = bucket[off + tid];
    for (int i = tid; i < WAVES * GMAX; i += THREADS) ((float*)rowpart)[i] = 0.f;
    __syncthreads();

    const int NT = (cnt + 15) >> 4;   // 16x16 tiles per side (1..4)
    const int T  = NT * NT;

    const int t0 = wv;                // this wave's tile slots
    const int t1 = wv + WAVES;
    int it0 = 0, jt0 = 0, it1 = 0, jt1 = 0;
    if (t0 < T) { it0 = t0 / NT; jt0 = t0 - it0 * NT; }
    if (t1 < T) { it1 = t1 / NT; jt1 = t1 - it1 * NT; }

    const int l15 = lane & 15;
    const int lh  = lane >> 4;        // 0..3

    f32x4 acc0 = {0.f, 0.f, 0.f, 0.f};
    f32x4 acc1 = {0.f, 0.f, 0.f, 0.f};

    for (int ch = 0; ch < NCHUNK; ++ch) {
        // ---- stage K-chunk: fp32 -> bf16 hi + bf16 lo residual ----
        for (int c = tid; c < cnt * (KC / 4); c += THREADS) {
            const int row = c >> 5;                // KC/4 == 32
            const int c4  = c & 31;
            const float4 v = *(const float4*)(z + (size_t)ids_sh[row] * D_DIM + ch * KC + c4 * 4);
            const unsigned int h0 = f2bf(v.x), h1 = f2bf(v.y), h2 = f2bf(v.z), h3 = f2bf(v.w);
            const unsigned int g0 = f2bf(v.x - bfval(h0));
            const unsigned int g1 = f2bf(v.y - bfval(h1));
            const unsigned int g2 = f2bf(v.z - bfval(h2));
            const unsigned int g3 = f2bf(v.w - bfval(h3));
            *(uint2*)&hi_sh[row][c4 * 4] = make_uint2(h0 | (h1 << 16), h2 | (h3 << 16));
            *(uint2*)&lo_sh[row][c4 * 4] = make_uint2(g0 | (g1 << 16), g2 | (g3 << 16));
        }
        __syncthreads();

        // ---- MFMA accumulate owned tiles: dot ~= hh + hl + lh ----
        if (t0 < T) {
            #pragma unroll
            for (int k4 = 0; k4 < KC / 32; ++k4) {
                const int kb = k4 * 32 + lh * 8;
                const bf16x8 ah = *(const bf16x8*)&hi_sh[it0 * 16 + l15][kb];
                const bf16x8 al = *(const bf16x8*)&lo_sh[it0 * 16 + l15][kb];
                const bf16x8 bh = *(const bf16x8*)&hi_sh[jt0 * 16 + l15][kb];
                const bf16x8 bl = *(const bf16x8*)&lo_sh[jt0 * 16 + l15][kb];
                acc0 = __builtin_amdgcn_mfma_f32_16x16x32_bf16(ah, bh, acc0, 0, 0, 0);
                acc0 = __builtin_amdgcn_mfma_f32_16x16x32_bf16(ah, bl, acc0, 0, 0, 0);
                acc0 = __builtin_amdgcn_mfma_f32_16x16x32_bf16(al, bh, acc0, 0, 0, 0);
            }
        }
        if (t1 < T) {
            #pragma unroll
            for (int k4 = 0; k4 < KC / 32; ++k4) {
                const int kb = k4 * 32 + lh * 8;
                const bf16x8 ah = *(const bf16x8*)&hi_sh[it1 * 16 + l15][kb];
                const bf16x8 al = *(const bf16x8*)&lo_sh[it1 * 16 + l15][kb];
                const bf16x8 bh = *(const bf16x8*)&hi_sh[jt1 * 16 + l15][kb];
                const bf16x8 bl = *(const bf16x8*)&lo_sh[jt1 * 16 + l15][kb];
                acc1 = __builtin_amdgcn_mfma_f32_16x16x32_bf16(ah, bh, acc1, 0, 0, 0);
                acc1 = __builtin_amdgcn_mfma_f32_16x16x32_bf16(ah, bl, acc1, 0, 0, 0);
                acc1 = __builtin_amdgcn_mfma_f32_16x16x32_bf16(al, bh, acc1, 0, 0, 0);
            }
        }
        __syncthreads();  // before next chunk overwrites LDS
    }

    // ---- pass A: diagonal of gram = |z_hat|^2 (consistent quantization) ----
    // C/D layout (m89-verified): col = lane&15, row = (lane>>4)*4 + reg
    if (t0 < T && it0 == jt0) {
        #pragma unroll
        for (int r = 0; r < 4; ++r) {
            const int drow = lh * 4 + r;
            if (l15 == drow) sq_sh[it0 * 16 + drow] = acc0[r];
        }
    }
    if (t1 < T && it1 == jt1) {
        #pragma unroll
        for (int r = 0; r < 4; ++r) {
            const int drow = lh * 4 + r;
            if (l15 == drow) sq_sh[it1 * 16 + drow] = acc1[r];
        }
    }
    __syncthreads();

    // ---- pass B: distances + per-row sums ----
    if (t0 < T) {
        #pragma unroll
        for (int r = 0; r < 4; ++r) {
            const int gi = it0 * 16 + lh * 4 + r;
            const int gj = jt0 * 16 + l15;
            const float d2 = sq_sh[gi] + sq_sh[gj] - 2.f * acc0[r];
            const bool valid = (gi < cnt) && (gj < cnt) && (gi != gj) && (d2 > 0.f);
            float dist = valid ? sqrtf(d2) : 0.f;
            dist += __shfl_xor(dist, 1, 64);
            dist += __shfl_xor(dist, 2, 64);
            dist += __shfl_xor(dist, 4, 64);
            dist += __shfl_xor(dist, 8, 64);
            if (l15 == 0) rowpart[wv][gi] += dist;
        }
    }
    if (t1 < T) {
        #pragma unroll
        for (int r = 0; r < 4; ++r) {
            const int gi = it1 * 16 + lh * 4 + r;
            const int gj = jt1 * 16 + l15;
            const float d2 = sq_sh[gi] + sq_sh[gj] - 2.f * acc1[r];
            const bool valid = (gi < cnt) && (gj < cnt) && (gi != gj) && (d2 > 0.f);
            float dist = valid ? sqrtf(d2) : 0.f;
            dist += __shfl_xor(dist, 1, 64);
            dist += __shfl_xor(dist, 2, 64);
            dist += __shfl_xor(dist, 4, 64);
            dist += __shfl_xor(dist, 8, 64);
            if (l15 == 0) rowpart[wv][gi] += dist;
        }
    }
    __syncthreads();

    // ---- final reduce over waves + write ----
    if (tid < cnt) {
        float s = 0.f;
        #pragma unroll
        for (int w = 0; w < WAVES; ++w) s += rowpart[w][tid];
        out[ids_sh[tid]] = (cnt > 1) ? s / (float)(cnt - 1) : 0.f;
    }
}

// ---------------- launch ----------------
extern "C" void kernel_launch(void* const* d_in, const int* in_sizes, int n_in,
                              void* d_out, int out_size, void* d_ws, size_t ws_size,
                              hipStream_t stream) {
    const float* z  = (const float*)d_in[0];
    const int*   Mx = (const int*)d_in[1];
    float*       out = (float*)d_out;

    int* counts  = (int*)d_ws;           // [256]
    int* offsets = counts + N_LABELS;    // [256]
    int* bucket  = offsets + N_LABELS;   // [8192]

    bucket_kernel<<<N_LABELS, 256, 0, stream>>>(Mx, counts, offsets, bucket);
    loss_kernel<<<N_LABELS, THREADS, 0, stream>>>(z, counts, offsets, bucket, out);
}

// Round 5
// 18.265 us; speedup vs baseline: 4.6106x; 1.2528x over previous
//
#include <hip/hip_runtime.h>
#include <math.h>

#define B_ROWS 8192
#define D_DIM 512
#define N_LABELS 256
#define GMAX 64            // max group size on MFMA path (P[exceed] ~ 1e-6; exact fallback below)
#define KC 128             // K-chunk staged per LDS pass
#define NCHUNK (D_DIM / KC)
#define THREADS 512
#define WAVES 8
#define SEG (B_ROWS / WAVES)   // 1024 rows scanned per wave
#define LSTRIDE (KC + 8)   // 136 bf16 per row

typedef __attribute__((ext_vector_type(8))) short bf16x8;
typedef __attribute__((ext_vector_type(4))) float f32x4;

static __device__ __forceinline__ unsigned int f2bf(float f) {
    // RNE fp32 -> bf16 bits
    unsigned int u = __float_as_uint(f);
    return (u + 0x7FFFu + ((u >> 16) & 1u)) >> 16;
}
static __device__ __forceinline__ float bfval(unsigned int b) {
    return __uint_as_float(b << 16);
}

// Single fused kernel: one block per label.
// Phase 1: in-block bucketing (ballot scan of Mx, stable order) -> ids_sh.
// Phase 2/3: K-chunked bf16 hi/lo staging + MFMA gram (round-4-verified).
// Phase 4: distance epilogue using gram diagonal as |z|^2 (consistent quant).
__global__ __launch_bounds__(THREADS) void loss_kernel(const float* __restrict__ z,
                                                       const int* __restrict__ Mx,
                                                       float* __restrict__ out) {
    __shared__ __align__(16) unsigned short hi_sh[GMAX][LSTRIDE];
    __shared__ __align__(16) unsigned short lo_sh[GMAX][LSTRIDE];
    __shared__ int   ids_sh[GMAX];
    __shared__ float sq_sh[GMAX];
    __shared__ float rowpart[WAVES][GMAX];
    __shared__ int   wcnt[WAVES];
    __shared__ int   wbase[WAVES];
    __shared__ int   cnt_sh;

    const int lbl  = blockIdx.x;
    const int tid  = threadIdx.x;
    const int wv   = tid >> 6;
    const int lane = tid & 63;
    const int sb   = wv * SEG;

    // ---- phase 1a: per-wave segment match count ----
    int c = 0;
    for (int i = lane; i < SEG; i += 64) c += (Mx[sb + i] == lbl);
    c += __shfl_xor(c, 1, 64);
    c += __shfl_xor(c, 2, 64);
    c += __shfl_xor(c, 4, 64);
    c += __shfl_xor(c, 8, 64);
    c += __shfl_xor(c, 16, 64);
    c += __shfl_xor(c, 32, 64);
    if (lane == 0) wcnt[wv] = c;
    __syncthreads();
    if (tid == 0) {
        int b = 0;
        for (int w = 0; w < WAVES; ++w) { wbase[w] = b; b += wcnt[w]; }
        cnt_sh = b;
    }
    __syncthreads();
    const int cnt = cnt_sh;
    if (cnt <= 0) return;

    if (cnt > GMAX) {
        // exact fp32 fallback (never runs for this data; correctness guard)
        int k = 0;
        for (int i = 0; i < B_ROWS; ++i) {
            if (Mx[i] != lbl) continue;
            if ((k++ % WAVES) != wv) continue;
            float acc = 0.f;
            for (int j = 0; j < B_ROWS; ++j) {
                if (Mx[j] != lbl || j == i) continue;
                float s = 0.f;
                for (int d = lane; d < D_DIM; d += 64) {
                    const float t = z[(size_t)i * D_DIM + d] - z[(size_t)j * D_DIM + d];
                    s = fmaf(t, t, s);
                }
                s += __shfl_xor(s, 1, 64);
                s += __shfl_xor(s, 2, 64);
                s += __shfl_xor(s, 4, 64);
                s += __shfl_xor(s, 8, 64);
                s += __shfl_xor(s, 16, 64);
                s += __shfl_xor(s, 32, 64);
                acc += (s > 0.f) ? sqrtf(s) : 0.f;
            }
            if (lane == 0) out[i] = acc / (float)(cnt - 1);
        }
        return;
    }

    // ---- phase 1b: stable rank scatter into ids_sh ----
    {
        int pos = wbase[wv];
        const unsigned long long lower = (lane == 0) ? 0ull : ((1ull << lane) - 1ull);
        for (int i0 = 0; i0 < SEG; i0 += 64) {
            const bool m = (Mx[sb + i0 + lane] == lbl);
            const unsigned long long bal = __ballot(m);
            if (m) ids_sh[pos + __popcll(bal & lower)] = sb + i0 + lane;
            pos += __popcll(bal);
        }
    }
    for (int i = tid; i < WAVES * GMAX; i += THREADS) ((float*)rowpart)[i] = 0.f;
    __syncthreads();

    // ---- phase 2/3: K-chunked staging + MFMA gram ----
    const int NT = (cnt + 15) >> 4;   // 16x16 tiles per side (1..4)
    const int T  = NT * NT;

    const int t0 = wv;                // this wave's tile slots
    const int t1 = wv + WAVES;
    int it0 = 0, jt0 = 0, it1 = 0, jt1 = 0;
    if (t0 < T) { it0 = t0 / NT; jt0 = t0 - it0 * NT; }
    if (t1 < T) { it1 = t1 / NT; jt1 = t1 - it1 * NT; }

    const int l15 = lane & 15;
    const int lh  = lane >> 4;        // 0..3

    f32x4 acc0 = {0.f, 0.f, 0.f, 0.f};
    f32x4 acc1 = {0.f, 0.f, 0.f, 0.f};

    for (int ch = 0; ch < NCHUNK; ++ch) {
        // stage K-chunk: fp32 -> bf16 hi + bf16 lo residual
        for (int c2 = tid; c2 < cnt * (KC / 4); c2 += THREADS) {
            const int row = c2 >> 5;                // KC/4 == 32
            const int c4  = c2 & 31;
            const float4 v = *(const float4*)(z + (size_t)ids_sh[row] * D_DIM + ch * KC + c4 * 4);
            const unsigned int h0 = f2bf(v.x), h1 = f2bf(v.y), h2 = f2bf(v.z), h3 = f2bf(v.w);
            const unsigned int g0 = f2bf(v.x - bfval(h0));
            const unsigned int g1 = f2bf(v.y - bfval(h1));
            const unsigned int g2 = f2bf(v.z - bfval(h2));
            const unsigned int g3 = f2bf(v.w - bfval(h3));
            *(uint2*)&hi_sh[row][c4 * 4] = make_uint2(h0 | (h1 << 16), h2 | (h3 << 16));
            *(uint2*)&lo_sh[row][c4 * 4] = make_uint2(g0 | (g1 << 16), g2 | (g3 << 16));
        }
        __syncthreads();

        // MFMA accumulate owned tiles: dot ~= hh + hl + lh
        if (t0 < T) {
            #pragma unroll
            for (int k4 = 0; k4 < KC / 32; ++k4) {
                const int kb = k4 * 32 + lh * 8;
                const bf16x8 ah = *(const bf16x8*)&hi_sh[it0 * 16 + l15][kb];
                const bf16x8 al = *(const bf16x8*)&lo_sh[it0 * 16 + l15][kb];
                const bf16x8 bh = *(const bf16x8*)&hi_sh[jt0 * 16 + l15][kb];
                const bf16x8 bl = *(const bf16x8*)&lo_sh[jt0 * 16 + l15][kb];
                acc0 = __builtin_amdgcn_mfma_f32_16x16x32_bf16(ah, bh, acc0, 0, 0, 0);
                acc0 = __builtin_amdgcn_mfma_f32_16x16x32_bf16(ah, bl, acc0, 0, 0, 0);
                acc0 = __builtin_amdgcn_mfma_f32_16x16x32_bf16(al, bh, acc0, 0, 0, 0);
            }
        }
        if (t1 < T) {
            #pragma unroll
            for (int k4 = 0; k4 < KC / 32; ++k4) {
                const int kb = k4 * 32 + lh * 8;
                const bf16x8 ah = *(const bf16x8*)&hi_sh[it1 * 16 + l15][kb];
                const bf16x8 al = *(const bf16x8*)&lo_sh[it1 * 16 + l15][kb];
                const bf16x8 bh = *(const bf16x8*)&hi_sh[jt1 * 16 + l15][kb];
                const bf16x8 bl = *(const bf16x8*)&lo_sh[jt1 * 16 + l15][kb];
                acc1 = __builtin_amdgcn_mfma_f32_16x16x32_bf16(ah, bh, acc1, 0, 0, 0);
                acc1 = __builtin_amdgcn_mfma_f32_16x16x32_bf16(ah, bl, acc1, 0, 0, 0);
                acc1 = __builtin_amdgcn_mfma_f32_16x16x32_bf16(al, bh, acc1, 0, 0, 0);
            }
        }
        __syncthreads();  // before next chunk overwrites LDS
    }

    // ---- pass A: gram diagonal = |z_hat|^2 (consistent quantization) ----
    // C/D layout (m89-verified): col = lane&15, row = (lane>>4)*4 + reg
    if (t0 < T && it0 == jt0) {
        #pragma unroll
        for (int r = 0; r < 4; ++r) {
            const int drow = lh * 4 + r;
            if (l15 == drow) sq_sh[it0 * 16 + drow] = acc0[r];
        }
    }
    if (t1 < T && it1 == jt1) {
        #pragma unroll
        for (int r = 0; r < 4; ++r) {
            const int drow = lh * 4 + r;
            if (l15 == drow) sq_sh[it1 * 16 + drow] = acc1[r];
        }
    }
    __syncthreads();

    // ---- pass B: distances + per-row sums ----
    if (t0 < T) {
        #pragma unroll
        for (int r = 0; r < 4; ++r) {
            const int gi = it0 * 16 + lh * 4 + r;
            const int gj = jt0 * 16 + l15;
            const float d2 = sq_sh[gi] + sq_sh[gj] - 2.f * acc0[r];
            const bool valid = (gi < cnt) && (gj < cnt) && (gi != gj) && (d2 > 0.f);
            float dist = valid ? sqrtf(d2) : 0.f;
            dist += __shfl_xor(dist, 1, 64);
            dist += __shfl_xor(dist, 2, 64);
            dist += __shfl_xor(dist, 4, 64);
            dist += __shfl_xor(dist, 8, 64);
            if (l15 == 0) rowpart[wv][gi] += dist;
        }
    }
    if (t1 < T) {
        #pragma unroll
        for (int r = 0; r < 4; ++r) {
            const int gi = it1 * 16 + lh * 4 + r;
            const int gj = jt1 * 16 + l15;
            const float d2 = sq_sh[gi] + sq_sh[gj] - 2.f * acc1[r];
            const bool valid = (gi < cnt) && (gj < cnt) && (gi != gj) && (d2 > 0.f);
            float dist = valid ? sqrtf(d2) : 0.f;
            dist += __shfl_xor(dist, 1, 64);
            dist += __shfl_xor(dist, 2, 64);
            dist += __shfl_xor(dist, 4, 64);
            dist += __shfl_xor(dist, 8, 64);
            if (l15 == 0) rowpart[wv][gi] += dist;
        }
    }
    __syncthreads();

    // ---- final reduce over waves + write ----
    if (tid < cnt) {
        float s = 0.f;
        #pragma unroll
        for (int w = 0; w < WAVES; ++w) s += rowpart[w][tid];
        out[ids_sh[tid]] = (cnt > 1) ? s / (float)(cnt - 1) : 0.f;
    }
}

// ---------------- launch ----------------
extern "C" void kernel_launch(void* const* d_in, const int* in_sizes, int n_in,
                              void* d_out, int out_size, void* d_ws, size_t ws_size,
                              hipStream_t stream) {
    const float* z  = (const float*)d_in[0];
    const int*   Mx = (const int*)d_in[1];
    float*       out = (float*)d_out;

    loss_kernel<<<N_LABELS, THREADS, 0, stream>>>(z, Mx, out);
}

// Round 6
// 13.253 us; speedup vs baseline: 6.3541x; 1.3781x over previous
//
#include <hip/hip_runtime.h>
#include <math.h>

#define B_ROWS 8192
#define D_DIM 512
#define N_LABELS 256
#define GMAX 64              // max group size on MFMA path (P[exceed] ~ 1e-8; exact fallback below)
#define THREADS 1024
#define WAVES 16
#define SEG (B_ROWS / WAVES) // 512 rows scanned per wave
#define SITER (SEG / 64)     // 8 ballot iterations per wave
#define LSTRIDE (D_DIM + 8)  // 520 bf16 per row -> 1040 B (16B-aligned rows, 2-way bank alias only)

typedef __attribute__((ext_vector_type(8))) short bf16x8;
typedef __attribute__((ext_vector_type(4))) float f32x4;

static __device__ __forceinline__ unsigned int f2bf(float f) {
    // RNE fp32 -> bf16 bits
    unsigned int u = __float_as_uint(f);
    return (u + 0x7FFFu + ((u >> 16) & 1u)) >> 16;
}
static __device__ __forceinline__ float bfval(unsigned int b) {
    return __uint_as_float(b << 16);
}

// One block per label; 16 waves.
// P1: ballot-scan Mx once (masks cached in LDS) -> stable ids_sh.
// P2: single staging pass, whole group fp32 -> bf16 hi+lo in LDS (133 KB).
// P3: MFMA gram, upper-triangle tiles only, one 16x16 tile per wave.
// P4: distance epilogue; off-diag tiles add row sums AND column sums.
__global__ __launch_bounds__(THREADS) void loss_kernel(const float* __restrict__ z,
                                                       const int* __restrict__ Mx,
                                                       float* __restrict__ out) {
    __shared__ __align__(16) unsigned short hi_sh[GMAX][LSTRIDE]; // 66,560 B
    __shared__ __align__(16) unsigned short lo_sh[GMAX][LSTRIDE]; // 66,560 B
    __shared__ int   ids_sh[GMAX];
    __shared__ float sq_sh[GMAX];
    __shared__ float rowpart[WAVES][GMAX];                        // 4 KB
    __shared__ unsigned long long msk_sh[WAVES][SITER];           // 1 KB
    __shared__ int   wcnt[WAVES], wbase[WAVES];
    __shared__ int   cnt_sh;

    const int lbl  = blockIdx.x;
    const int tid  = threadIdx.x;
    const int wv   = tid >> 6;
    const int lane = tid & 63;
    const int sb   = wv * SEG;

    // ---- P1a: one scan; cache ballot masks ----
    int c = 0;
    #pragma unroll
    for (int t = 0; t < SITER; ++t) {
        const bool m = (Mx[sb + t * 64 + lane] == lbl);
        const unsigned long long bal = __ballot(m);
        if (lane == 0) msk_sh[wv][t] = bal;
        c += __popcll(bal);   // wave-uniform
    }
    if (lane == 0) wcnt[wv] = c;
    __syncthreads();
    if (tid == 0) {
        int b = 0;
        #pragma unroll
        for (int w = 0; w < WAVES; ++w) { wbase[w] = b; b += wcnt[w]; }
        cnt_sh = b;
    }
    __syncthreads();
    const int cnt = cnt_sh;
    if (cnt <= 0) return;

    if (cnt > GMAX) {
        // exact fp32 fallback (statistically never runs; correctness guard)
        int k = 0;
        for (int i = 0; i < B_ROWS; ++i) {
            if (Mx[i] != lbl) continue;
            if ((k++ % WAVES) != wv) continue;
            float acc = 0.f;
            for (int j = 0; j < B_ROWS; ++j) {
                if (Mx[j] != lbl || j == i) continue;
                float s = 0.f;
                for (int d = lane; d < D_DIM; d += 64) {
                    const float t = z[(size_t)i * D_DIM + d] - z[(size_t)j * D_DIM + d];
                    s = fmaf(t, t, s);
                }
                s += __shfl_xor(s, 1, 64);
                s += __shfl_xor(s, 2, 64);
                s += __shfl_xor(s, 4, 64);
                s += __shfl_xor(s, 8, 64);
                s += __shfl_xor(s, 16, 64);
                s += __shfl_xor(s, 32, 64);
                acc += (s > 0.f) ? sqrtf(s) : 0.f;
            }
            if (lane == 0) out[i] = acc / (float)(cnt - 1);
        }
        return;
    }

    // ---- P1b: stable rank scatter from cached masks (no Mx reload) ----
    {
        int pos = wbase[wv];
        const unsigned long long lower = (lane == 0) ? 0ull : ((1ull << lane) - 1ull);
        #pragma unroll
        for (int t = 0; t < SITER; ++t) {
            const unsigned long long bal = msk_sh[wv][t];
            if ((bal >> lane) & 1ull)
                ids_sh[pos + __popcll(bal & lower)] = sb + t * 64 + lane;
            pos += __popcll(bal);
        }
    }
    for (int i = tid; i < WAVES * GMAX; i += THREADS) ((float*)rowpart)[i] = 0.f;
    __syncthreads();

    // ---- P2: single staging pass, fp32 -> bf16 hi + lo residual ----
    for (int c2 = tid; c2 < cnt * (D_DIM / 4); c2 += THREADS) {
        const int row = c2 >> 7;              // D_DIM/4 == 128
        const int c4  = c2 & 127;
        const float4 v = *(const float4*)(z + (size_t)ids_sh[row] * D_DIM + c4 * 4);
        const unsigned int h0 = f2bf(v.x), h1 = f2bf(v.y), h2 = f2bf(v.z), h3 = f2bf(v.w);
        const unsigned int g0 = f2bf(v.x - bfval(h0));
        const unsigned int g1 = f2bf(v.y - bfval(h1));
        const unsigned int g2 = f2bf(v.z - bfval(h2));
        const unsigned int g3 = f2bf(v.w - bfval(h3));
        *(uint2*)&hi_sh[row][c4 * 4] = make_uint2(h0 | (h1 << 16), h2 | (h3 << 16));
        *(uint2*)&lo_sh[row][c4 * 4] = make_uint2(g0 | (g1 << 16), g2 | (g3 << 16));
    }
    __syncthreads();

    // ---- P3: MFMA gram, upper-triangle tiles, one tile per wave ----
    const int NT = (cnt + 15) >> 4;           // 1..4
    const int TS = NT * (NT + 1) / 2;         // 1,3,6,10

    int jt = 0;
    #pragma unroll
    for (int q = 1; q < 4; ++q) jt += (wv >= q * (q + 1) / 2);  // wv -> jt (col-major tri)
    const int it = wv - jt * (jt + 1) / 2;
    const bool own = (wv < TS);

    const int l15 = lane & 15;
    const int lh  = lane >> 4;                // 0..3

    f32x4 acc = {0.f, 0.f, 0.f, 0.f};
    if (own) {
        #pragma unroll
        for (int k4 = 0; k4 < D_DIM / 32; ++k4) {
            const int kb = k4 * 32 + lh * 8;
            const bf16x8 ah = *(const bf16x8*)&hi_sh[it * 16 + l15][kb];
            const bf16x8 al = *(const bf16x8*)&lo_sh[it * 16 + l15][kb];
            const bf16x8 bh = *(const bf16x8*)&hi_sh[jt * 16 + l15][kb];
            const bf16x8 bl = *(const bf16x8*)&lo_sh[jt * 16 + l15][kb];
            acc = __builtin_amdgcn_mfma_f32_16x16x32_bf16(ah, bh, acc, 0, 0, 0);
            acc = __builtin_amdgcn_mfma_f32_16x16x32_bf16(ah, bl, acc, 0, 0, 0);
            acc = __builtin_amdgcn_mfma_f32_16x16x32_bf16(al, bh, acc, 0, 0, 0);
        }
    }

    // ---- P4a: gram diagonal = |z_hat|^2 (diagonal tiles only) ----
    // C/D layout (m89-verified): col = lane&15, row = (lane>>4)*4 + reg
    if (own && it == jt) {
        #pragma unroll
        for (int r = 0; r < 4; ++r) {
            const int drow = lh * 4 + r;
            if (l15 == drow) sq_sh[it * 16 + drow] = acc[r];
        }
    }
    __syncthreads();

    // ---- P4b: distances; row sums + (off-diag) column sums ----
    if (own) {
        float d0 = 0.f, d1 = 0.f, d2v = 0.f, d3 = 0.f;
        #pragma unroll
        for (int r = 0; r < 4; ++r) {
            const int gi = it * 16 + lh * 4 + r;
            const int gj = jt * 16 + l15;
            const float d2 = sq_sh[gi] + sq_sh[gj] - 2.f * acc[r];
            const bool valid = (gi < cnt) && (gj < cnt) && (gi != gj) && (d2 > 0.f);
            const float dist = valid ? sqrtf(d2) : 0.f;
            if (r == 0) d0 = dist; else if (r == 1) d1 = dist; else if (r == 2) d2v = dist; else d3 = dist;

            float rs = dist;
            rs += __shfl_xor(rs, 1, 64);
            rs += __shfl_xor(rs, 2, 64);
            rs += __shfl_xor(rs, 4, 64);
            rs += __shfl_xor(rs, 8, 64);
            if (l15 == 0) rowpart[wv][gi] += rs;
        }
        if (it != jt) {
            float cs = (d0 + d1) + (d2v + d3);  // sum over this lane's 4 rows
            cs += __shfl_xor(cs, 16, 64);
            cs += __shfl_xor(cs, 32, 64);       // now sum over all 16 rows of the tile
            if (lane < 16) rowpart[wv][jt * 16 + l15] += cs;
        }
    }
    __syncthreads();

    // ---- final reduce over waves + write ----
    if (tid < cnt) {
        float s = 0.f;
        #pragma unroll
        for (int w = 0; w < WAVES; ++w) s += rowpart[w][tid];
        out[ids_sh[tid]] = (cnt > 1) ? s / (float)(cnt - 1) : 0.f;
    }
}

// ---------------- launch ----------------
extern "C" void kernel_launch(void* const* d_in, const int* in_sizes, int n_in,
                              void* d_out, int out_size, void* d_ws, size_t ws_size,
                              hipStream_t stream) {
    const float* z  = (const float*)d_in[0];
    const int*   Mx = (const int*)d_in[1];
    float*       out = (float*)d_out;

    loss_kernel<<<N_LABELS, THREADS, 0, stream>>>(z, Mx, out);
}

// Round 7
// 12.945 us; speedup vs baseline: 6.5056x; 1.0238x over previous
//
#include <hip/hip_runtime.h>
#include <math.h>

#define B_ROWS 8192
#define D_DIM 512
#define N_LABELS 256
#define GMAX 64              // max group size on MFMA path (P[exceed] ~ 1e-6; exact fallback below)
#define THREADS 1024
#define WAVES 16
#define SEG (B_ROWS / WAVES) // 512 rows scanned per wave
#define SITER (SEG / 64)     // 8 ballot iterations per wave
#define LSTRIDE (D_DIM + 8)  // 520 fp16 per row -> 1040 B stride (16B-aligned, 2-way bank alias only)

typedef __attribute__((ext_vector_type(8))) _Float16 f16x8;
typedef __attribute__((ext_vector_type(4))) float f32x4;

static __device__ __forceinline__ unsigned short f2h(float f) {
    const _Float16 h = (_Float16)f;       // v_cvt_f16_f32 (RNE)
    return __builtin_bit_cast(unsigned short, h);
}

// One block per label; 16 waves; single fused kernel.
// P1: ballot-scan Mx once (masks cached in LDS) -> stable ids_sh.
// P2: single staging pass, whole group fp32 -> fp16 in LDS (67 KB).
// P3: MFMA fp16 gram, upper-triangle tiles, one 16x16 tile per wave.
// P4: distance epilogue; off-diag tiles add row sums AND column sums.
__global__ __launch_bounds__(THREADS) void loss_kernel(const float* __restrict__ z,
                                                       const int* __restrict__ Mx,
                                                       float* __restrict__ out) {
    __shared__ __align__(16) unsigned short h_sh[GMAX][LSTRIDE];  // 66,560 B
    __shared__ int   ids_sh[GMAX];
    __shared__ float sq_sh[GMAX];
    __shared__ float rowpart[WAVES][GMAX];                        // 4 KB
    __shared__ unsigned long long msk_sh[WAVES][SITER];           // 1 KB
    __shared__ int   wcnt[WAVES], wbase[WAVES];
    __shared__ int   cnt_sh;

    const int lbl  = blockIdx.x;
    const int tid  = threadIdx.x;
    const int wv   = tid >> 6;
    const int lane = tid & 63;
    const int sb   = wv * SEG;

    // ---- P1a: one scan; cache ballot masks ----
    int c = 0;
    #pragma unroll
    for (int t = 0; t < SITER; ++t) {
        const bool m = (Mx[sb + t * 64 + lane] == lbl);
        const unsigned long long bal = __ballot(m);
        if (lane == 0) msk_sh[wv][t] = bal;
        c += __popcll(bal);   // wave-uniform
    }
    if (lane == 0) wcnt[wv] = c;
    __syncthreads();

    // parallel 16-lane inclusive scan in wave 0
    if (wv == 0) {
        int v = (lane < WAVES) ? wcnt[lane] : 0;
        #pragma unroll
        for (int d = 1; d < WAVES; d <<= 1) {
            const int o = __shfl_up(v, d, 64);
            if (lane >= d) v += o;
        }
        if (lane < WAVES) wbase[lane] = v - wcnt[lane];
        if (lane == WAVES - 1) cnt_sh = v;
    }
    __syncthreads();
    const int cnt = cnt_sh;
    if (cnt <= 0) return;

    if (cnt > GMAX) {
        // exact fp32 fallback (statistically never runs; correctness guard)
        int k = 0;
        for (int i = 0; i < B_ROWS; ++i) {
            if (Mx[i] != lbl) continue;
            if ((k++ % WAVES) != wv) continue;
            float acc = 0.f;
            for (int j = 0; j < B_ROWS; ++j) {
                if (Mx[j] != lbl || j == i) continue;
                float s = 0.f;
                for (int d = lane; d < D_DIM; d += 64) {
                    const float t = z[(size_t)i * D_DIM + d] - z[(size_t)j * D_DIM + d];
                    s = fmaf(t, t, s);
                }
                s += __shfl_xor(s, 1, 64);
                s += __shfl_xor(s, 2, 64);
                s += __shfl_xor(s, 4, 64);
                s += __shfl_xor(s, 8, 64);
                s += __shfl_xor(s, 16, 64);
                s += __shfl_xor(s, 32, 64);
                acc += (s > 0.f) ? sqrtf(s) : 0.f;
            }
            if (lane == 0) out[i] = acc / (float)(cnt - 1);
        }
        return;
    }

    // ---- P1b: stable rank scatter from cached masks (no Mx reload) ----
    {
        int pos = wbase[wv];
        const unsigned long long lower = (lane == 0) ? 0ull : ((1ull << lane) - 1ull);
        #pragma unroll
        for (int t = 0; t < SITER; ++t) {
            const unsigned long long bal = msk_sh[wv][t];
            if ((bal >> lane) & 1ull)
                ids_sh[pos + __popcll(bal & lower)] = sb + t * 64 + lane;
            pos += __popcll(bal);
        }
    }
    for (int i = tid; i < WAVES * GMAX; i += THREADS) ((float*)rowpart)[i] = 0.f;
    __syncthreads();

    // ---- P2: single staging pass, fp32 -> fp16 ----
    for (int c2 = tid; c2 < cnt * (D_DIM / 4); c2 += THREADS) {
        const int row = c2 >> 7;              // D_DIM/4 == 128
        const int c4  = c2 & 127;
        const float4 v = *(const float4*)(z + (size_t)ids_sh[row] * D_DIM + c4 * 4);
        const unsigned int p0 = (unsigned int)f2h(v.x) | ((unsigned int)f2h(v.y) << 16);
        const unsigned int p1 = (unsigned int)f2h(v.z) | ((unsigned int)f2h(v.w) << 16);
        *(uint2*)&h_sh[row][c4 * 4] = make_uint2(p0, p1);
    }
    __syncthreads();

    // ---- P3: MFMA fp16 gram, upper-triangle tiles, one tile per wave ----
    const int NT = (cnt + 15) >> 4;           // 1..4
    const int TS = NT * (NT + 1) / 2;         // 1,3,6,10

    int jt = 0;
    #pragma unroll
    for (int q = 1; q < 4; ++q) jt += (wv >= q * (q + 1) / 2);  // wv -> (it,jt) col-major tri
    const int it = wv - jt * (jt + 1) / 2;
    const bool own = (wv < TS);

    const int l15 = lane & 15;
    const int lh  = lane >> 4;                // 0..3

    f32x4 acc = {0.f, 0.f, 0.f, 0.f};
    if (own) {
        #pragma unroll
        for (int k4 = 0; k4 < D_DIM / 32; ++k4) {
            const int kb = k4 * 32 + lh * 8;
            const f16x8 a = *(const f16x8*)&h_sh[it * 16 + l15][kb];
            const f16x8 b = *(const f16x8*)&h_sh[jt * 16 + l15][kb];
            acc = __builtin_amdgcn_mfma_f32_16x16x32_f16(a, b, acc, 0, 0, 0);
        }
    }

    // ---- P4a: gram diagonal = |z_hat|^2 (diagonal tiles only) ----
    // C/D layout (m89-verified): col = lane&15, row = (lane>>4)*4 + reg
    if (own && it == jt) {
        #pragma unroll
        for (int r = 0; r < 4; ++r) {
            const int drow = lh * 4 + r;
            if (l15 == drow) sq_sh[it * 16 + drow] = acc[r];
        }
    }
    __syncthreads();

    // ---- P4b: distances; row sums + (off-diag) column sums ----
    if (own) {
        float d0 = 0.f, d1 = 0.f, d2v = 0.f, d3 = 0.f;
        #pragma unroll
        for (int r = 0; r < 4; ++r) {
            const int gi = it * 16 + lh * 4 + r;
            const int gj = jt * 16 + l15;
            const float d2 = sq_sh[gi] + sq_sh[gj] - 2.f * acc[r];
            const bool valid = (gi < cnt) && (gj < cnt) && (gi != gj) && (d2 > 0.f);
            const float dist = valid ? sqrtf(d2) : 0.f;
            if (r == 0) d0 = dist; else if (r == 1) d1 = dist; else if (r == 2) d2v = dist; else d3 = dist;

            float rs = dist;
            rs += __shfl_xor(rs, 1, 64);
            rs += __shfl_xor(rs, 2, 64);
            rs += __shfl_xor(rs, 4, 64);
            rs += __shfl_xor(rs, 8, 64);
            if (l15 == 0) rowpart[wv][gi] += rs;
        }
        if (it != jt) {
            float cs = (d0 + d1) + (d2v + d3);  // sum over this lane's 4 rows
            cs += __shfl_xor(cs, 16, 64);
            cs += __shfl_xor(cs, 32, 64);       // sum over all 16 rows of the tile
            if (lane < 16) rowpart[wv][jt * 16 + l15] += cs;
        }
    }
    __syncthreads();

    // ---- final reduce over waves + write ----
    if (tid < cnt) {
        float s = 0.f;
        #pragma unroll
        for (int w = 0; w < WAVES; ++w) s += rowpart[w][tid];
        out[ids_sh[tid]] = (cnt > 1) ? s / (float)(cnt - 1) : 0.f;
    }
}

// ---------------- launch ----------------
extern "C" void kernel_launch(void* const* d_in, const int* in_sizes, int n_in,
                              void* d_out, int out_size, void* d_ws, size_t ws_size,
                              hipStream_t stream) {
    const float* z  = (const float*)d_in[0];
    const int*   Mx = (const int*)d_in[1];
    float*       out = (float*)d_out;

    loss_kernel<<<N_LABELS, THREADS, 0, stream>>>(z, Mx, out);
}